// Round 6
// baseline (201.887 us; speedup 1.0000x reference)
//
#include <hip/hip_runtime.h>
#include <math.h>

// Problem constants (fixed by the reference)
#define BN_NODES 16384     // B*N
#define DIM 128            // D
#define HID 256            // H
#define TK 2048            // distance-table knots
#define TRANGE 32.0f
#define TSTEP (TRANGE / (float)TK)   // 1/64
#define TINV  ((float)TK / TRANGE)   // 64
#define LN_EPS 1e-5f
#define EPB 4096           // edges per block in binA
#define CAPR 1024          // LDS edge-record capacity per 16-node group (mean 512)

typedef __attribute__((ext_vector_type(8))) short bf16x8;
typedef __attribute__((ext_vector_type(4))) float f32x4;
typedef __attribute__((ext_vector_type(8))) unsigned short ushort8v;

__device__ __forceinline__ unsigned short f2bf(float f) {
    unsigned int u = __float_as_uint(f);
    u += 0x7fffu + ((u >> 16) & 1u);           // RNE
    return (unsigned short)(u >> 16);
}
__device__ __forceinline__ float bf2f(unsigned short s) {
    return __uint_as_float(((unsigned int)s) << 16);
}

// ---------------------------------------------------------------------------
// K1 "prep" (fused): blocks 0..255 build bf16 filter table Tb[2048][128];
// 256..319 transpose W3 -> w3t[n][k] bf16; 320..351 transpose W4 -> w4t[n][k];
// 352..1375 convert h -> xb (contiguous [node][128] bf16); 1376.. histogram.
__global__ __launch_bounds__(256) void prep_kernel(
        const float* __restrict__ W1, const float* __restrict__ b1,
        const float* __restrict__ W2, const float* __restrict__ b2,
        const float* __restrict__ W3, const float* __restrict__ W4,
        const float* __restrict__ h, const int* __restrict__ ei,
        unsigned short* __restrict__ Tb, unsigned short* __restrict__ w3t,
        unsigned short* __restrict__ w4t, unsigned short* __restrict__ xb,
        int* __restrict__ counts, int nE) {
    __shared__ float smem[8 * 256 + 8 * 128];   // 12 KB, role-dependent
    int bid = blockIdx.x, t = threadIdx.x;
    if (bid < 256) {
        float* a    = smem;          // [8][256]
        float* part = smem + 2048;   // [8][128]
        int k0 = bid * 8;
        float w1 = W1[t], bb = b1[t];
#pragma unroll
        for (int k = 0; k < 8; ++k) {
            float dist = (float)(k0 + k) * TSTEP;
            float z = dist * w1 + bb;
            a[k * 256 + t] = z / (1.0f + expf(-z));
        }
        __syncthreads();
        int hg = t >> 7, d = t & 127;
        float acc[8] = {0.f,0.f,0.f,0.f,0.f,0.f,0.f,0.f};
        for (int hh = 0; hh < 128; ++hh) {
            int hidx = hg * 128 + hh;
            float w = W2[hidx * DIM + d];
#pragma unroll
            for (int k = 0; k < 8; ++k) acc[k] += a[k * 256 + hidx] * w;
        }
        if (hg == 1) {
#pragma unroll
            for (int k = 0; k < 8; ++k) part[k * 128 + d] = acc[k];
        }
        __syncthreads();
        if (hg == 0) {
            float bd = b2[d];
#pragma unroll
            for (int k = 0; k < 8; ++k)
                Tb[(k0 + k) * DIM + d] = f2bf(acc[k] + part[k * 128 + d] + bd);
        }
    } else if (bid < 320) {
        float* s = smem;   // [32][33]
        int tid = bid - 256, tr = tid >> 3, tc = tid & 7;
        int lr = t >> 5, lc = t & 31;
#pragma unroll
        for (int rep = 0; rep < 4; ++rep) {
            int k = tr * 32 + rep * 8 + lr, n = tc * 32 + lc;
            s[lc * 33 + rep * 8 + lr] = W3[k * 256 + n];
        }
        __syncthreads();
#pragma unroll
        for (int rep = 0; rep < 4; ++rep) {
            int n = tc * 32 + rep * 8 + lr, k = tr * 32 + lc;
            w3t[n * 256 + k] = f2bf(s[(rep * 8 + lr) * 33 + lc]);
        }
    } else if (bid < 352) {
        float* s = smem;
        int tid = bid - 320, tr = tid >> 2, tc = tid & 3;
        int lr = t >> 5, lc = t & 31;
#pragma unroll
        for (int rep = 0; rep < 4; ++rep) {
            int k = tr * 32 + rep * 8 + lr, n = tc * 32 + lc;
            s[lc * 33 + rep * 8 + lr] = W4[k * 128 + n];
        }
        __syncthreads();
#pragma unroll
        for (int rep = 0; rep < 4; ++rep) {
            int n = tc * 32 + rep * 8 + lr, k = tr * 32 + lc;
            w4t[n * 256 + k] = f2bf(s[(rep * 8 + lr) * 33 + lc]);
        }
    } else if (bid < 1376) {
        int i0 = (bid - 352) * 2048 + t * 8;
        float4 v0 = *(const float4*)&h[i0];
        float4 v1 = *(const float4*)&h[i0 + 4];
        ushort8v o;
        o[0] = f2bf(v0.x); o[1] = f2bf(v0.y); o[2] = f2bf(v0.z); o[3] = f2bf(v0.w);
        o[4] = f2bf(v1.x); o[5] = f2bf(v1.y); o[6] = f2bf(v1.z); o[7] = f2bf(v1.w);
        *(ushort8v*)&xb[i0] = o;
    } else {
        int e = (bid - 1376) * 256 + t;
        if (e < nE) atomicAdd(&counts[ei[e]], 1);
    }
}

// ---------------------------------------------------------------------------
// K2: exclusive scan over 16384 counts (1024 threads, 16 each) + bin cursors
__global__ void scan_kernel(const int* __restrict__ counts, int* __restrict__ offsets,
                            int* __restrict__ bin_cursor) {
    __shared__ int s[1024];
    int t = threadIdx.x;
    int base = t * 16;
    int sum = 0;
#pragma unroll
    for (int i = 0; i < 4; ++i) {
        int4 v = *(const int4*)&counts[base + i * 4];
        sum += v.x + v.y + v.z + v.w;
    }
    s[t] = sum;
    __syncthreads();
    for (int off = 1; off < 1024; off <<= 1) {
        int v = (t >= off) ? s[t - off] : 0;
        __syncthreads();
        s[t] += v;
        __syncthreads();
    }
    int run = (t == 0) ? 0 : s[t - 1];
    for (int i = 0; i < 16; ++i) {
        int c = counts[base + i];
        offsets[base + i] = run;
        run += c;
    }
    if (t == 1023) offsets[BN_NODES] = run;
    __syncthreads();
    if (t < 256) bin_cursor[t] = offsets[t * 64];
}

// ---------------------------------------------------------------------------
// K3: bin scatter + dist. LDS counting-sort 4096-edge chunks into 256 bins
// (bin = row>>6); during write-out compute dist (16-deep unrolled loop gives
// good MLP for the random x gathers) and emit uint2 (row<<16|col, dist) to
// per-bin staging. Keeps writes in bursty per-bin runs (no line blow-up).
__global__ __launch_bounds__(256) void binA_kernel(
        const int* __restrict__ ei, const float* __restrict__ x,
        int* __restrict__ bin_cursor, uint2* __restrict__ staging, int nE) {
    __shared__ int cnt[256];
    __shared__ int pre[256];
    __shared__ int gbase[256];
    __shared__ unsigned int rec[EPB];   // 16 KB
    int t = threadIdx.x;
    int e0 = blockIdx.x * EPB;
    int m = min(EPB, nE - e0);
    cnt[t] = 0;
    __syncthreads();
    unsigned int code[16];
    int rk[16], bn[16];
#pragma unroll
    for (int j = 0; j < 16; ++j) {
        int idx = j * 256 + t;
        rk[j] = -1; bn[j] = 0; code[j] = 0;
        if (idx < m) {
            int e = e0 + idx;
            int r = ei[e], c = ei[nE + e];
            code[j] = ((unsigned int)r << 16) | (unsigned int)c;
            bn[j] = r >> 6;
            rk[j] = atomicAdd(&cnt[bn[j]], 1);
        }
    }
    __syncthreads();
    int v = cnt[t];
    pre[t] = v;
    __syncthreads();
    for (int off = 1; off < 256; off <<= 1) {
        int add = (t >= off) ? pre[t - off] : 0;
        __syncthreads();
        pre[t] += add;
        __syncthreads();
    }
    int excl = pre[t] - v;
    __syncthreads();
    pre[t] = excl;
    gbase[t] = atomicAdd(&bin_cursor[t], v);
    __syncthreads();
#pragma unroll
    for (int j = 0; j < 16; ++j)
        if (rk[j] >= 0) rec[pre[bn[j]] + rk[j]] = code[j];
    __syncthreads();
    for (int i = t; i < m; i += 256) {
        unsigned int cd = rec[i];
        int b = cd >> 22;               // row >> 6
        int r = (int)(cd >> 16);
        int c = (int)(cd & 0xffffu);
        float dx = x[r * 3 + 0] - x[c * 3 + 0];
        float dy = x[r * 3 + 1] - x[c * 3 + 1];
        float dz = x[r * 3 + 2] - x[c * 3 + 2];
        float dist = sqrtf(dx * dx + dy * dy + dz * dz);
        uint2 o; o.x = cd; o.y = __float_as_uint(dist);
        staging[gbase[b] + (i - pre[b])] = o;
    }
}

// ---------------------------------------------------------------------------
// K4 "fused" v2: 512 threads / 8 waves (round-5's 4-wave version was
// latency-bound at 31% occupancy: VALUBusy 43%, HBM 6%, MfmaUtil 2%).
// One block per 16 nodes. Phase 1: filter this bin's staging slice (dist
// precomputed in binA) into LDS CSR. Phase 2: 8 waves x 2 nodes gather
// (xb rows + Tb interp) -> agg in LDS. Phase 3: MFMA GEMM1 (8 waves x 32
// cols) -> LN -> SiLU -> GEMM2 (8 waves x 16 cols) -> out.
__global__ __launch_bounds__(512, 8) void fused_kernel(
        const uint2* __restrict__ staging, const int* __restrict__ offsets,
        const unsigned short* __restrict__ xb, const unsigned short* __restrict__ Tb,
        const unsigned short* __restrict__ w3t, const float* __restrict__ b3,
        const float* __restrict__ gamma, const float* __restrict__ beta,
        const unsigned short* __restrict__ w4t, const float* __restrict__ b4,
        float* __restrict__ out) {
    __shared__ uint2 lrec[CAPR];                               // 8 KB
    __shared__ int pref[17];
    __shared__ int cur[16];
    __shared__ __align__(16) unsigned short agg_lds[16][136];  // 272B stride -> 2-way only
    __shared__ __align__(16) unsigned short a_lds[16][264];    // 528B stride -> 2-way only
    __shared__ float part_s[8][16], part_q[8][16];

    int t = threadIdx.x;
    int n0 = blockIdx.x * 16;
    int bin0 = n0 & ~63;
    if (t < 17) pref[t] = offsets[n0 + t] - offsets[n0];
    if (t < 16) cur[t]  = offsets[n0 + t] - offsets[n0];
    int s0 = offsets[bin0], s1 = offsets[bin0 + 64];
    __syncthreads();
    int cnt16 = pref[16];
    bool fits = (cnt16 <= CAPR);

    // ---- phase 1: bin slice -> LDS records (CSR order); no x access needed
    if (fits) {
        for (int i = s0 + t; i < s1; i += 512) {
            uint2 rc = staging[i];
            int r = (int)(rc.x >> 16);
            if ((unsigned)(r - n0) < 16u) {
                int pos = atomicAdd(&cur[r - n0], 1);
                uint2 rr; rr.x = rc.x & 0xffffu; rr.y = rc.y;
                lrec[pos] = rr;
            }
        }
    }
    __syncthreads();

    // ---- phase 2: wave wv owns nodes wv*2, wv*2+1
    int wv = t >> 6, lane = t & 63, dd = lane * 2;
#pragma unroll
    for (int jj = 0; jj < 2; ++jj) {
        int j = wv * 2 + jj;
        int off0 = pref[j], off1 = pref[j + 1];
        float a0 = 0.f, a1 = 0.f;
        if (fits) {
            int i = off0;
            for (; i + 4 <= off1; i += 4) {
                uint2 e0 = lrec[i], e1 = lrec[i + 1], e2 = lrec[i + 2], e3 = lrec[i + 3];
                float u0 = __uint_as_float(e0.y) * TINV;
                float u1 = __uint_as_float(e1.y) * TINV;
                float u2 = __uint_as_float(e2.y) * TINV;
                float u3 = __uint_as_float(e3.y) * TINV;
                int k0 = min((int)u0, TK - 2); float f0 = u0 - (float)k0;
                int k1 = min((int)u1, TK - 2); float f1 = u1 - (float)k1;
                int k2 = min((int)u2, TK - 2); float f2 = u2 - (float)k2;
                int k3 = min((int)u3, TK - 2); float f3 = u3 - (float)k3;
                unsigned int h0 = *(const unsigned int*)&xb[e0.x * DIM + dd];
                unsigned int h1 = *(const unsigned int*)&xb[e1.x * DIM + dd];
                unsigned int h2 = *(const unsigned int*)&xb[e2.x * DIM + dd];
                unsigned int h3 = *(const unsigned int*)&xb[e3.x * DIM + dd];
                unsigned int A0 = *(const unsigned int*)&Tb[k0 * DIM + dd];
                unsigned int B0 = *(const unsigned int*)&Tb[k0 * DIM + DIM + dd];
                unsigned int A1 = *(const unsigned int*)&Tb[k1 * DIM + dd];
                unsigned int B1 = *(const unsigned int*)&Tb[k1 * DIM + DIM + dd];
                unsigned int A2 = *(const unsigned int*)&Tb[k2 * DIM + dd];
                unsigned int B2 = *(const unsigned int*)&Tb[k2 * DIM + DIM + dd];
                unsigned int A3 = *(const unsigned int*)&Tb[k3 * DIM + dd];
                unsigned int B3 = *(const unsigned int*)&Tb[k3 * DIM + DIM + dd];
                float ax, bx, ay, by;
                ax = bf2f((unsigned short)A0); bx = bf2f((unsigned short)(A0 >> 16));
                ay = bf2f((unsigned short)B0); by = bf2f((unsigned short)(B0 >> 16));
                a0 += bf2f((unsigned short)h0)         * (ax + (ay - ax) * f0);
                a1 += bf2f((unsigned short)(h0 >> 16)) * (bx + (by - bx) * f0);
                ax = bf2f((unsigned short)A1); bx = bf2f((unsigned short)(A1 >> 16));
                ay = bf2f((unsigned short)B1); by = bf2f((unsigned short)(B1 >> 16));
                a0 += bf2f((unsigned short)h1)         * (ax + (ay - ax) * f1);
                a1 += bf2f((unsigned short)(h1 >> 16)) * (bx + (by - bx) * f1);
                ax = bf2f((unsigned short)A2); bx = bf2f((unsigned short)(A2 >> 16));
                ay = bf2f((unsigned short)B2); by = bf2f((unsigned short)(B2 >> 16));
                a0 += bf2f((unsigned short)h2)         * (ax + (ay - ax) * f2);
                a1 += bf2f((unsigned short)(h2 >> 16)) * (bx + (by - bx) * f2);
                ax = bf2f((unsigned short)A3); bx = bf2f((unsigned short)(A3 >> 16));
                ay = bf2f((unsigned short)B3); by = bf2f((unsigned short)(B3 >> 16));
                a0 += bf2f((unsigned short)h3)         * (ax + (ay - ax) * f3);
                a1 += bf2f((unsigned short)(h3 >> 16)) * (bx + (by - bx) * f3);
            }
            for (; i < off1; ++i) {
                uint2 ev = lrec[i];
                float u = __uint_as_float(ev.y) * TINV;
                int k = min((int)u, TK - 2);
                float f = u - (float)k;
                unsigned int hv = *(const unsigned int*)&xb[ev.x * DIM + dd];
                unsigned int Av = *(const unsigned int*)&Tb[k * DIM + dd];
                unsigned int Bv = *(const unsigned int*)&Tb[k * DIM + DIM + dd];
                float ax = bf2f((unsigned short)Av), bx = bf2f((unsigned short)(Av >> 16));
                float ay = bf2f((unsigned short)Bv), by = bf2f((unsigned short)(Bv >> 16));
                a0 += bf2f((unsigned short)hv)         * (ax + (ay - ax) * f);
                a1 += bf2f((unsigned short)(hv >> 16)) * (bx + (by - bx) * f);
            }
        } else {
            // slow-but-safe overflow path: broadcast-scan the whole bin slice
            for (int i = s0; i < s1; ++i) {
                uint2 rc = staging[i];
                if ((int)(rc.x >> 16) != n0 + j) continue;
                int c = (int)(rc.x & 0xffffu);
                float u = __uint_as_float(rc.y) * TINV;
                int k = min((int)u, TK - 2);
                float f = u - (float)k;
                unsigned int hv = *(const unsigned int*)&xb[c * DIM + dd];
                unsigned int Av = *(const unsigned int*)&Tb[k * DIM + dd];
                unsigned int Bv = *(const unsigned int*)&Tb[k * DIM + DIM + dd];
                float ax = bf2f((unsigned short)Av), bx = bf2f((unsigned short)(Av >> 16));
                float ay = bf2f((unsigned short)Bv), by = bf2f((unsigned short)(Bv >> 16));
                a0 += bf2f((unsigned short)hv)         * (ax + (ay - ax) * f);
                a1 += bf2f((unsigned short)(hv >> 16)) * (bx + (by - bx) * f);
            }
        }
        float inv = 1.0f / (float)max(off1 - off0, 1);
        unsigned int packed = (unsigned int)f2bf(a0 * inv)
                            | ((unsigned int)f2bf(a1 * inv) << 16);
        *(unsigned int*)&agg_lds[j][dd] = packed;
    }
    __syncthreads();

    // ---- phase 3: GEMM1 (M=16, N=256, K=256); wave wv owns cols wv*32..+31
    int q = lane >> 4, l15 = lane & 15;
    f32x4 acc[2];
#pragma unroll
    for (int nt = 0; nt < 2; ++nt) acc[nt] = (f32x4){0.f, 0.f, 0.f, 0.f};
    for (int kc = 0; kc < 8; ++kc) {
        bf16x8 a;
        if (kc < 4) a = *(const bf16x8*)&xb[(n0 + l15) * DIM + kc * 32 + q * 8];
        else        a = *(const bf16x8*)&agg_lds[l15][(kc - 4) * 32 + q * 8];
#pragma unroll
        for (int nt = 0; nt < 2; ++nt) {
            bf16x8 b = *(const bf16x8*)&w3t[(wv * 32 + nt * 16 + l15) * 256 + kc * 32 + q * 8];
            acc[nt] = __builtin_amdgcn_mfma_f32_16x16x32_bf16(a, b, acc[nt], 0, 0, 0);
        }
    }

    // bias + LN stats (wave partial over its 32 cols)
    float b3v[2], gv[2], bv[2];
#pragma unroll
    for (int nt = 0; nt < 2; ++nt) {
        int col = wv * 32 + nt * 16 + l15;
        b3v[nt] = b3[col]; gv[nt] = gamma[col]; bv[nt] = beta[col];
    }
    float s[4], ss[4];   // per reg (row = q*4+reg)
#pragma unroll
    for (int reg = 0; reg < 4; ++reg) {
        float su = 0.f, sq = 0.f;
#pragma unroll
        for (int nt = 0; nt < 2; ++nt) {
            float v = acc[nt][reg] + b3v[nt];
            acc[nt][reg] = v;
            su += v; sq += v * v;
        }
        s[reg] = su; ss[reg] = sq;
    }
#pragma unroll
    for (int off = 1; off < 16; off <<= 1) {
#pragma unroll
        for (int reg = 0; reg < 4; ++reg) {
            s[reg]  += __shfl_xor(s[reg],  off, 64);
            ss[reg] += __shfl_xor(ss[reg], off, 64);
        }
    }
    if (l15 == 0) {
#pragma unroll
        for (int reg = 0; reg < 4; ++reg) {
            int r = q * 4 + reg;
            part_s[wv][r] = s[reg];
            part_q[wv][r] = ss[reg];
        }
    }
    __syncthreads();

    // LN + SiLU -> bf16 act in LDS (A-operand layout [m][k])
#pragma unroll
    for (int reg = 0; reg < 4; ++reg) {
        int r = q * 4 + reg;
        float st = 0.f, qt = 0.f;
#pragma unroll
        for (int w = 0; w < 8; ++w) { st += part_s[w][r]; qt += part_q[w][r]; }
        float mu = st * (1.0f / 256.0f);
        float var = qt * (1.0f / 256.0f) - mu * mu;
        float rs = rsqrtf(var + LN_EPS);
#pragma unroll
        for (int nt = 0; nt < 2; ++nt) {
            float un = (acc[nt][reg] - mu) * rs * gv[nt] + bv[nt];
            float act = un / (1.0f + expf(-un));
            a_lds[r][wv * 32 + nt * 16 + l15] = f2bf(act);
        }
    }
    __syncthreads();

    // GEMM2 (M=16, N=128, K=256); wave wv owns cols wv*16..+15
    f32x4 acc2 = (f32x4){0.f, 0.f, 0.f, 0.f};
    for (int kc = 0; kc < 8; ++kc) {
        bf16x8 a = *(const bf16x8*)&a_lds[l15][kc * 32 + q * 8];
        bf16x8 b = *(const bf16x8*)&w4t[(wv * 16 + l15) * 256 + kc * 32 + q * 8];
        acc2 = __builtin_amdgcn_mfma_f32_16x16x32_bf16(a, b, acc2, 0, 0, 0);
    }
    float b4v = b4[wv * 16 + l15];
#pragma unroll
    for (int reg = 0; reg < 4; ++reg) {
        int node = n0 + q * 4 + reg;
        out[node * DIM + wv * 16 + l15] = acc2[reg] + b4v;
    }
}

// ---------------------------------------------------------------------------
extern "C" void kernel_launch(void* const* d_in, const int* in_sizes, int n_in,
                              void* d_out, int out_size, void* d_ws, size_t ws_size,
                              hipStream_t stream) {
    const float* x     = (const float*)d_in[0];
    const float* h     = (const float*)d_in[1];
    const int*   ei    = (const int*)d_in[2];
    const float* W1    = (const float*)d_in[4];
    const float* b1    = (const float*)d_in[5];
    const float* W2    = (const float*)d_in[6];
    const float* b2    = (const float*)d_in[7];
    const float* W3    = (const float*)d_in[8];
    const float* b3    = (const float*)d_in[9];
    const float* gamma = (const float*)d_in[10];
    const float* beta  = (const float*)d_in[11];
    const float* W4    = (const float*)d_in[12];
    const float* b4    = (const float*)d_in[13];
    float* out = (float*)d_out;
    int nE = in_sizes[2] / 2;

    char* ws = (char*)d_ws;
    unsigned short* Tb  = (unsigned short*)ws; ws += (size_t)TK * DIM * 2;       // 512 KB
    unsigned short* w3t = (unsigned short*)ws; ws += (size_t)HID * HID * 2;      // 128 KB
    unsigned short* w4t = (unsigned short*)ws; ws += (size_t)DIM * HID * 2;      // 64 KB
    unsigned short* xb  = (unsigned short*)ws; ws += (size_t)BN_NODES * DIM * 2; // 4 MB
    int*   counts     = (int*)ws;          ws += (size_t)BN_NODES * 4;
    int*   offsets    = (int*)ws;          ws += (size_t)(BN_NODES + 128) * 4;
    int*   bin_cursor = (int*)ws;          ws += 256 * 4;
    uint2* staging    = (uint2*)ws;        ws += (size_t)nE * 8;                 // 4 MB

    int histBlocks = (nE + 255) / 256;
    int binABlocks = (nE + EPB - 1) / EPB;
    hipMemsetAsync(counts, 0, (size_t)BN_NODES * 4, stream);
    prep_kernel<<<1376 + histBlocks, 256, 0, stream>>>(W1, b1, W2, b2, W3, W4, h, ei,
                                                       Tb, w3t, w4t, xb, counts, nE);
    scan_kernel<<<1, 1024, 0, stream>>>(counts, offsets, bin_cursor);
    binA_kernel<<<binABlocks, 256, 0, stream>>>(ei, x, bin_cursor, staging, nE);
    fused_kernel<<<BN_NODES / 16, 512, 0, stream>>>(staging, offsets, xb, Tb,
                                                    w3t, b3, gamma, beta, w4t, b4, out);
}

// Round 7
// 192.682 us; speedup vs baseline: 1.0478x; 1.0478x over previous
//
#include <hip/hip_runtime.h>
#include <hip/hip_fp16.h>
#include <math.h>

// Problem constants (fixed by the reference)
#define BN_NODES 16384     // B*N
#define DIM 128            // D
#define HID 256            // H
#define TK 2048            // distance-table knots
#define TRANGE 32.0f
#define TSTEP (TRANGE / (float)TK)   // 1/64
#define TINV  ((float)TK / TRANGE)   // 64
#define LN_EPS 1e-5f
#define EPB 4096           // edges per block in binA

typedef _Float16 f16x8 __attribute__((ext_vector_type(8)));
typedef __attribute__((ext_vector_type(4))) float f32x4;
typedef __attribute__((ext_vector_type(8))) unsigned short ushort8v;

__device__ __forceinline__ unsigned short f2h(float f) {
    _Float16 h = (_Float16)f;          // v_cvt_f16_f32, RNE
    return *(unsigned short*)&h;
}

// ---------------------------------------------------------------------------
// K1 "prep" (fused): blocks 0..255 build fp16 filter table Tb[2048][128];
// 256..319 transpose W3 -> w3t[n][k] fp16; 320..351 transpose W4 -> w4t[n][k];
// 352..1375 convert h -> xh (contiguous [node][128] fp16); 1376.. histogram.
__global__ __launch_bounds__(256) void prep_kernel(
        const float* __restrict__ W1, const float* __restrict__ b1,
        const float* __restrict__ W2, const float* __restrict__ b2,
        const float* __restrict__ W3, const float* __restrict__ W4,
        const float* __restrict__ h, const int* __restrict__ ei,
        unsigned short* __restrict__ Tb, unsigned short* __restrict__ w3t,
        unsigned short* __restrict__ w4t, unsigned short* __restrict__ xh,
        int* __restrict__ counts, int nE) {
    __shared__ float smem[8 * 256 + 8 * 128];   // 12 KB, role-dependent
    int bid = blockIdx.x, t = threadIdx.x;
    if (bid < 256) {
        float* a    = smem;          // [8][256]
        float* part = smem + 2048;   // [8][128]
        int k0 = bid * 8;
        float w1 = W1[t], bb = b1[t];
#pragma unroll
        for (int k = 0; k < 8; ++k) {
            float dist = (float)(k0 + k) * TSTEP;
            float z = dist * w1 + bb;
            a[k * 256 + t] = z / (1.0f + expf(-z));
        }
        __syncthreads();
        int hg = t >> 7, d = t & 127;
        float acc[8] = {0.f,0.f,0.f,0.f,0.f,0.f,0.f,0.f};
        for (int hh = 0; hh < 128; ++hh) {
            int hidx = hg * 128 + hh;
            float w = W2[hidx * DIM + d];
#pragma unroll
            for (int k = 0; k < 8; ++k) acc[k] += a[k * 256 + hidx] * w;
        }
        if (hg == 1) {
#pragma unroll
            for (int k = 0; k < 8; ++k) part[k * 128 + d] = acc[k];
        }
        __syncthreads();
        if (hg == 0) {
            float bd = b2[d];
#pragma unroll
            for (int k = 0; k < 8; ++k)
                Tb[(k0 + k) * DIM + d] = f2h(acc[k] + part[k * 128 + d] + bd);
        }
    } else if (bid < 320) {
        float* s = smem;   // [32][33]
        int tid = bid - 256, tr = tid >> 3, tc = tid & 7;
        int lr = t >> 5, lc = t & 31;
#pragma unroll
        for (int rep = 0; rep < 4; ++rep) {
            int k = tr * 32 + rep * 8 + lr, n = tc * 32 + lc;
            s[lc * 33 + rep * 8 + lr] = W3[k * 256 + n];
        }
        __syncthreads();
#pragma unroll
        for (int rep = 0; rep < 4; ++rep) {
            int n = tc * 32 + rep * 8 + lr, k = tr * 32 + lc;
            w3t[n * 256 + k] = f2h(s[(rep * 8 + lr) * 33 + lc]);
        }
    } else if (bid < 352) {
        float* s = smem;
        int tid = bid - 320, tr = tid >> 2, tc = tid & 3;
        int lr = t >> 5, lc = t & 31;
#pragma unroll
        for (int rep = 0; rep < 4; ++rep) {
            int k = tr * 32 + rep * 8 + lr, n = tc * 32 + lc;
            s[lc * 33 + rep * 8 + lr] = W4[k * 128 + n];
        }
        __syncthreads();
#pragma unroll
        for (int rep = 0; rep < 4; ++rep) {
            int n = tc * 32 + rep * 8 + lr, k = tr * 32 + lc;
            w4t[n * 256 + k] = f2h(s[(rep * 8 + lr) * 33 + lc]);
        }
    } else if (bid < 1376) {
        int i0 = (bid - 352) * 2048 + t * 8;
        float4 v0 = *(const float4*)&h[i0];
        float4 v1 = *(const float4*)&h[i0 + 4];
        ushort8v o;
        o[0] = f2h(v0.x); o[1] = f2h(v0.y); o[2] = f2h(v0.z); o[3] = f2h(v0.w);
        o[4] = f2h(v1.x); o[5] = f2h(v1.y); o[6] = f2h(v1.z); o[7] = f2h(v1.w);
        *(ushort8v*)&xh[i0] = o;
    } else {
        int e = (bid - 1376) * 256 + t;
        if (e < nE) atomicAdd(&counts[ei[e]], 1);
    }
}

// ---------------------------------------------------------------------------
// K2: exclusive scan over 16384 counts (1024 threads, 16 each) + bin cursors
__global__ void scan_kernel(const int* __restrict__ counts, int* __restrict__ offsets,
                            int* __restrict__ bin_cursor) {
    __shared__ int s[1024];
    int t = threadIdx.x;
    int base = t * 16;
    int sum = 0;
#pragma unroll
    for (int i = 0; i < 4; ++i) {
        int4 v = *(const int4*)&counts[base + i * 4];
        sum += v.x + v.y + v.z + v.w;
    }
    s[t] = sum;
    __syncthreads();
    for (int off = 1; off < 1024; off <<= 1) {
        int v = (t >= off) ? s[t - off] : 0;
        __syncthreads();
        s[t] += v;
        __syncthreads();
    }
    int run = (t == 0) ? 0 : s[t - 1];
    for (int i = 0; i < 16; ++i) {
        int c = counts[base + i];
        offsets[base + i] = run;
        run += c;
    }
    if (t == 1023) offsets[BN_NODES] = run;
    __syncthreads();
    if (t < 256) bin_cursor[t] = offsets[t * 64];
}

// ---------------------------------------------------------------------------
// K3: bin scatter + edge precompute. LDS counting-sort 4096-edge chunks into
// 256 bins (bin = row>>6); at write-out compute dist -> table knot k and
// fp16 frac, emit uint2 (r<<16|c, k<<16|frac_bits) to per-bin staging.
// (Per-bin bursty writes avoid the 13x line write amplification of random
// scatter across non-coherent XCD L2s.)
__global__ __launch_bounds__(256) void binA_kernel(
        const int* __restrict__ ei, const float* __restrict__ x,
        int* __restrict__ bin_cursor, uint2* __restrict__ staging, int nE) {
    __shared__ int cnt[256];
    __shared__ int pre[256];
    __shared__ int gbase[256];
    __shared__ unsigned int rec[EPB];   // 16 KB
    int t = threadIdx.x;
    int e0 = blockIdx.x * EPB;
    int m = min(EPB, nE - e0);
    cnt[t] = 0;
    __syncthreads();
    unsigned int code[16];
    int rk[16], bn[16];
#pragma unroll
    for (int j = 0; j < 16; ++j) {
        int idx = j * 256 + t;
        rk[j] = -1; bn[j] = 0; code[j] = 0;
        if (idx < m) {
            int e = e0 + idx;
            int r = ei[e], c = ei[nE + e];
            code[j] = ((unsigned int)r << 16) | (unsigned int)c;
            bn[j] = r >> 6;
            rk[j] = atomicAdd(&cnt[bn[j]], 1);
        }
    }
    __syncthreads();
    int v = cnt[t];
    pre[t] = v;
    __syncthreads();
    for (int off = 1; off < 256; off <<= 1) {
        int add = (t >= off) ? pre[t - off] : 0;
        __syncthreads();
        pre[t] += add;
        __syncthreads();
    }
    int excl = pre[t] - v;
    __syncthreads();
    pre[t] = excl;
    gbase[t] = atomicAdd(&bin_cursor[t], v);
    __syncthreads();
#pragma unroll
    for (int j = 0; j < 16; ++j)
        if (rk[j] >= 0) rec[pre[bn[j]] + rk[j]] = code[j];
    __syncthreads();
    for (int i = t; i < m; i += 256) {
        unsigned int cd = rec[i];
        int b = (int)(cd >> 22);            // row >> 6
        int r = (int)(cd >> 16);
        int c = (int)(cd & 0xffffu);
        float dx = x[r * 3 + 0] - x[c * 3 + 0];
        float dy = x[r * 3 + 1] - x[c * 3 + 1];
        float dz = x[r * 3 + 2] - x[c * 3 + 2];
        float u = sqrtf(dx * dx + dy * dy + dz * dz) * TINV;
        int k = min((int)u, TK - 2);
        float frac = u - (float)k;
        uint2 o;
        o.x = cd;
        o.y = ((unsigned int)k << 16) | (unsigned int)f2h(frac);
        staging[gbase[b] + (i - pre[b])] = o;
    }
}

// ---------------------------------------------------------------------------
// K4: binB — one block per bin; reorder staging slice into CSR order.
// erec = (c | k<<16, frac duplicated into both fp16 halves). All writes in
// this block's 16 KB window -> lines fill in one XCD L2.
__global__ __launch_bounds__(256) void binB_kernel(
        const uint2* __restrict__ staging, const int* __restrict__ offsets,
        uint2* __restrict__ erec) {
    __shared__ int cur[64];
    int t = threadIdx.x;
    int bin = blockIdx.x;
    int s0 = offsets[bin * 64];
    int s1 = offsets[bin * 64 + 64];
    if (t < 64) cur[t] = offsets[bin * 64 + t];
    __syncthreads();
    for (int i = s0 + t; i < s1; i += 256) {
        uint2 sr = staging[i];
        int r = (int)(sr.x >> 16);
        int pos = atomicAdd(&cur[r & 63], 1);
        uint2 o;
        o.x = (sr.x & 0xffffu) | (sr.y & 0xffff0000u);   // c | k<<16
        o.y = (sr.y & 0xffffu) * 0x10001u;               // frac2 (both halves)
        erec[pos] = o;
    }
}

// ---------------------------------------------------------------------------
// K5: agg — one block per node, 4 waves split the edge list. Per edge:
// 1 wave-uniform erec load (broadcast) + 3 dword gathers (h pair, table A
// pair; B row at +256B imm offset) + 3 packed-fp16 ops. fp32 flush every
// 4 edges bounds fp16 accumulation error. LDS cross-wave reduce.
__global__ __launch_bounds__(256) void agg_kernel(
        const int* __restrict__ offsets, const uint2* __restrict__ erec,
        const unsigned short* __restrict__ Tb, const unsigned short* __restrict__ xh,
        unsigned short* __restrict__ aggb) {
    __shared__ float red[3][DIM];
    int wave = threadIdx.x >> 6;
    int lane = threadIdx.x & 63;
    int node = blockIdx.x;
    int off0 = offsets[node], off1 = offsets[node + 1];
    int deg = off1 - off0;
    int qd = (deg + 3) >> 2;
    int start = off0 + wave * qd;
    int end = min(off1, start + qd);
    int dd = lane * 2;
    float a0 = 0.f, a1 = 0.f;

    const __half2 zero2 = __float2half2_rn(0.f);
    int i = start;
    for (; i + 4 <= end; i += 4) {
        uint2 e0 = erec[i], e1 = erec[i + 1], e2 = erec[i + 2], e3 = erec[i + 3];
        __half2 acch = zero2;
#pragma unroll
        for (int j = 0; j < 4; ++j) {
            uint2 e = (j == 0) ? e0 : (j == 1) ? e1 : (j == 2) ? e2 : e3;
            int c = (int)(e.x & 0xffffu);
            int k = (int)(e.x >> 16);
            __half2 frac2 = *(__half2*)&e.y;
            __half2 h2 = *(const __half2*)&xh[c * DIM + dd];
            __half2 A2 = *(const __half2*)&Tb[k * DIM + dd];
            __half2 B2 = *(const __half2*)&Tb[k * DIM + DIM + dd];
            __half2 f2 = __hfma2(__hsub2(B2, A2), frac2, A2);
            acch = __hfma2(h2, f2, acch);
        }
        a0 += __low2float(acch);
        a1 += __high2float(acch);
    }
    {
        __half2 acch = zero2;
        for (; i < end; ++i) {
            uint2 e = erec[i];
            int c = (int)(e.x & 0xffffu);
            int k = (int)(e.x >> 16);
            __half2 frac2 = *(__half2*)&e.y;
            __half2 h2 = *(const __half2*)&xh[c * DIM + dd];
            __half2 A2 = *(const __half2*)&Tb[k * DIM + dd];
            __half2 B2 = *(const __half2*)&Tb[k * DIM + DIM + dd];
            __half2 f2 = __hfma2(__hsub2(B2, A2), frac2, A2);
            acch = __hfma2(h2, f2, acch);
        }
        a0 += __low2float(acch);
        a1 += __high2float(acch);
    }

    if (wave > 0) { red[wave - 1][dd] = a0; red[wave - 1][dd + 1] = a1; }
    __syncthreads();
    if (wave == 0) {
        a0 += red[0][dd]     + red[1][dd]     + red[2][dd];
        a1 += red[0][dd + 1] + red[1][dd + 1] + red[2][dd + 1];
        float inv = 1.0f / (float)max(deg, 1);
        unsigned int packed = (unsigned int)f2h(a0 * inv)
                            | ((unsigned int)f2h(a1 * inv) << 16);
        *(unsigned int*)&aggb[node * DIM + dd] = packed;
    }
}

// ---------------------------------------------------------------------------
// K6: fused node update via MFMA fp16 (C/D layout dtype-independent, m89).
// Block = 64 nodes, 4 waves. GEMM1: U[64,256] = [xh|aggb] @ W3 (wave owns 64
// cols). LN stats via intra-quad shfl + LDS partials. Act -> fp16 LDS
// (A-layout). GEMM2: out[64,128] = act @ W4 (wave owns 32 cols).
__global__ __launch_bounds__(256) void node_kernel(
        const unsigned short* __restrict__ xh, const unsigned short* __restrict__ aggb,
        const unsigned short* __restrict__ w3t, const float* __restrict__ b3,
        const float* __restrict__ gamma, const float* __restrict__ beta,
        const unsigned short* __restrict__ w4t, const float* __restrict__ b4,
        float* __restrict__ out) {
    __shared__ __align__(16) unsigned short a_lds[64][264];  // act fp16, 33 KB
    __shared__ float part_s[4][64];
    __shared__ float part_q[4][64];
    int t = threadIdx.x;
    int wv = t >> 6, lane = t & 63;
    int q = lane >> 4, l15 = lane & 15;
    int n0 = blockIdx.x * 64;

    // ---- GEMM1
    f32x4 acc[4][4];
#pragma unroll
    for (int mt = 0; mt < 4; ++mt)
#pragma unroll
        for (int nt = 0; nt < 4; ++nt)
            acc[mt][nt] = (f32x4){0.f, 0.f, 0.f, 0.f};

    for (int kc = 0; kc < 8; ++kc) {
        f16x8 a[4];
#pragma unroll
        for (int mt = 0; mt < 4; ++mt) {
            int row = n0 + mt * 16 + l15;
            if (kc < 4) a[mt] = *(const f16x8*)&xh[row * DIM + kc * 32 + q * 8];
            else        a[mt] = *(const f16x8*)&aggb[row * DIM + (kc - 4) * 32 + q * 8];
        }
#pragma unroll
        for (int nt = 0; nt < 4; ++nt) {
            f16x8 b = *(const f16x8*)&w3t[(wv * 64 + nt * 16 + l15) * 256 + kc * 32 + q * 8];
#pragma unroll
            for (int mt = 0; mt < 4; ++mt)
                acc[mt][nt] = __builtin_amdgcn_mfma_f32_16x16x32_f16(a[mt], b, acc[mt][nt], 0, 0, 0);
        }
    }

    // ---- bias + LN stats
    float b3v[4], gv[4], bv[4];
#pragma unroll
    for (int nt = 0; nt < 4; ++nt) {
        int col = wv * 64 + nt * 16 + l15;
        b3v[nt] = b3[col]; gv[nt] = gamma[col]; bv[nt] = beta[col];
    }
    float s[4][4], ss[4][4];   // [mt][reg]
#pragma unroll
    for (int mt = 0; mt < 4; ++mt)
#pragma unroll
        for (int reg = 0; reg < 4; ++reg) {
            float su = 0.f, sq = 0.f;
#pragma unroll
            for (int nt = 0; nt < 4; ++nt) {
                float v = acc[mt][nt][reg] + b3v[nt];
                acc[mt][nt][reg] = v;
                su += v; sq += v * v;
            }
            s[mt][reg] = su; ss[mt][reg] = sq;
        }
#pragma unroll
    for (int off = 1; off < 16; off <<= 1) {
#pragma unroll
        for (int mt = 0; mt < 4; ++mt)
#pragma unroll
            for (int reg = 0; reg < 4; ++reg) {
                s[mt][reg]  += __shfl_xor(s[mt][reg],  off, 64);
                ss[mt][reg] += __shfl_xor(ss[mt][reg], off, 64);
            }
    }
    if (l15 == 0) {
#pragma unroll
        for (int mt = 0; mt < 4; ++mt)
#pragma unroll
            for (int reg = 0; reg < 4; ++reg) {
                int r = mt * 16 + q * 4 + reg;
                part_s[wv][r] = s[mt][reg];
                part_q[wv][r] = ss[mt][reg];
            }
    }
    __syncthreads();

    // ---- LN + SiLU -> fp16 act in LDS (A-operand layout [m][k])
#pragma unroll
    for (int mt = 0; mt < 4; ++mt)
#pragma unroll
        for (int reg = 0; reg < 4; ++reg) {
            int r = mt * 16 + q * 4 + reg;
            float st = part_s[0][r] + part_s[1][r] + part_s[2][r] + part_s[3][r];
            float qt = part_q[0][r] + part_q[1][r] + part_q[2][r] + part_q[3][r];
            float mu = st * (1.0f / 256.0f);
            float var = qt * (1.0f / 256.0f) - mu * mu;
            float rs = rsqrtf(var + LN_EPS);
#pragma unroll
            for (int nt = 0; nt < 4; ++nt) {
                float un = (acc[mt][nt][reg] - mu) * rs * gv[nt] + bv[nt];
                float act = un / (1.0f + expf(-un));
                a_lds[r][wv * 64 + nt * 16 + l15] = f2h(act);
            }
        }
    __syncthreads();

    // ---- GEMM2
    f32x4 acc2[4][2];
#pragma unroll
    for (int mt = 0; mt < 4; ++mt)
#pragma unroll
        for (int nt = 0; nt < 2; ++nt)
            acc2[mt][nt] = (f32x4){0.f, 0.f, 0.f, 0.f};
    for (int kc = 0; kc < 8; ++kc) {
        f16x8 a[4];
#pragma unroll
        for (int mt = 0; mt < 4; ++mt)
            a[mt] = *(const f16x8*)&a_lds[mt * 16 + l15][kc * 32 + q * 8];
#pragma unroll
        for (int nt = 0; nt < 2; ++nt) {
            f16x8 b = *(const f16x8*)&w4t[(wv * 32 + nt * 16 + l15) * 256 + kc * 32 + q * 8];
#pragma unroll
            for (int mt = 0; mt < 4; ++mt)
                acc2[mt][nt] = __builtin_amdgcn_mfma_f32_16x16x32_f16(a[mt], b, acc2[mt][nt], 0, 0, 0);
        }
    }
    float b4v[2];
#pragma unroll
    for (int nt = 0; nt < 2; ++nt) b4v[nt] = b4[wv * 32 + nt * 16 + l15];
#pragma unroll
    for (int mt = 0; mt < 4; ++mt)
#pragma unroll
        for (int nt = 0; nt < 2; ++nt)
#pragma unroll
            for (int reg = 0; reg < 4; ++reg) {
                int node = n0 + mt * 16 + q * 4 + reg;
                out[node * DIM + wv * 32 + nt * 16 + l15] = acc2[mt][nt][reg] + b4v[nt];
            }
}

// ---------------------------------------------------------------------------
extern "C" void kernel_launch(void* const* d_in, const int* in_sizes, int n_in,
                              void* d_out, int out_size, void* d_ws, size_t ws_size,
                              hipStream_t stream) {
    const float* x     = (const float*)d_in[0];
    const float* h     = (const float*)d_in[1];
    const int*   ei    = (const int*)d_in[2];
    const float* W1    = (const float*)d_in[4];
    const float* b1    = (const float*)d_in[5];
    const float* W2    = (const float*)d_in[6];
    const float* b2    = (const float*)d_in[7];
    const float* W3    = (const float*)d_in[8];
    const float* b3    = (const float*)d_in[9];
    const float* gamma = (const float*)d_in[10];
    const float* beta  = (const float*)d_in[11];
    const float* W4    = (const float*)d_in[12];
    const float* b4    = (const float*)d_in[13];
    float* out = (float*)d_out;
    int nE = in_sizes[2] / 2;

    char* ws = (char*)d_ws;
    unsigned short* Tb   = (unsigned short*)ws; ws += (size_t)TK * DIM * 2;       // 512 KB
    unsigned short* w3t  = (unsigned short*)ws; ws += (size_t)HID * HID * 2;      // 128 KB
    unsigned short* w4t  = (unsigned short*)ws; ws += (size_t)DIM * HID * 2;      // 64 KB
    unsigned short* xh   = (unsigned short*)ws; ws += (size_t)BN_NODES * DIM * 2; // 4 MB
    unsigned short* aggb = (unsigned short*)ws; ws += (size_t)BN_NODES * DIM * 2; // 4 MB
    int*   counts     = (int*)ws;          ws += (size_t)BN_NODES * 4;
    int*   offsets    = (int*)ws;          ws += (size_t)(BN_NODES + 128) * 4;
    int*   bin_cursor = (int*)ws;          ws += 256 * 4;
    uint2* staging    = (uint2*)ws;        ws += (size_t)nE * 8;                  // 4 MB
    uint2* erec       = (uint2*)ws;        ws += (size_t)nE * 8;                  // 4 MB

    int histBlocks = (nE + 255) / 256;
    int binABlocks = (nE + EPB - 1) / EPB;
    hipMemsetAsync(counts, 0, (size_t)BN_NODES * 4, stream);
    prep_kernel<<<1376 + histBlocks, 256, 0, stream>>>(W1, b1, W2, b2, W3, W4, h, ei,
                                                       Tb, w3t, w4t, xh, counts, nE);
    scan_kernel<<<1, 1024, 0, stream>>>(counts, offsets, bin_cursor);
    binA_kernel<<<binABlocks, 256, 0, stream>>>(ei, x, bin_cursor, staging, nE);
    binB_kernel<<<256, 256, 0, stream>>>(staging, offsets, erec);
    agg_kernel<<<BN_NODES, 256, 0, stream>>>(offsets, erec, Tb, xh, aggb);
    node_kernel<<<BN_NODES / 64, 256, 0, stream>>>(xh, aggb, w3t, b3, gamma, beta, w4t, b4, out);
}